// Round 16
// baseline (1099.320 us; speedup 1.0000x reference)
//
#include <hip/hip_runtime.h>
#include <math.h>
#include <stdint.h>

// GPT fwd, L=4 D=1024 H=16 HS=64 F=4096 V=50257 S=2048.
// Round 16: R15 base + FFN2 split-K 2->4 (1024 blocks = 100% fill),
// reduce_ln templated on partial count, pffn2 relocated to wsb+76MB.
// Everything else byte-identical to R15 (1086.9 us).

#define SEQ 2048
#define DIM 1024
#define NHEAD 16
#define FFN 4096
#define VOCAB 50257
#define NLAYER 4
#define LNEPS 1e-5f
#define QKVD 3072
#define KVB 128

using bf16x8 = __attribute__((ext_vector_type(8))) short;
using s16x4  = __attribute__((ext_vector_type(4))) short;
using f32x4  = __attribute__((ext_vector_type(4))) float;
using fl4    = __attribute__((ext_vector_type(4))) float;

static __device__ __forceinline__ short f2bf(float f) {
  uint32_t u = __float_as_uint(f);
  u = (u + 0x7fffu + ((u >> 16) & 1u)) >> 16;
  return (short)u;
}
static __device__ __forceinline__ float bf2f(short s) {
  return __uint_as_float(((uint32_t)(uint16_t)s) << 16);
}
static __device__ __forceinline__ void gload_lds16(const void* g, void* l) {
  __builtin_amdgcn_global_load_lds((const __attribute__((address_space(1))) void*)g,
                                   (__attribute__((address_space(3))) void*)l, 16, 0, 0);
}

// ---------------- embedding (fp32 h) ----------------
__global__ void embed_kernel(const int* __restrict__ ids,
                             const float* __restrict__ tok,
                             const float* __restrict__ pos,
                             float* __restrict__ h) {
  int i = blockIdx.x * blockDim.x + threadIdx.x;
  if (i < SEQ * DIM) {
    int s = i / DIM, d = i % DIM;
    h[i] = tok[(long)ids[s] * DIM + d] + pos[i];
  }
}

// ---------------- layernorm: fp32 in -> bf16 out (layer0 ln1 only) ----------------
__global__ void ln_kernel(const float* __restrict__ x, const float* __restrict__ w,
                          const float* __restrict__ b, short* __restrict__ y) {
  int row = blockIdx.x;
  const float* xr = x + (long)row * DIM;
  short* yr = y + (long)row * DIM;
  int tid = threadIdx.x;
  float v0 = xr[tid], v1 = xr[tid + 256], v2 = xr[tid + 512], v3 = xr[tid + 768];
  __shared__ float red[8];
  float s = v0 + v1 + v2 + v3;
#pragma unroll
  for (int o = 32; o >= 1; o >>= 1) s += __shfl_xor(s, o);
  if ((tid & 63) == 0) red[tid >> 6] = s;
  __syncthreads();
  float mean = (red[0] + red[1] + red[2] + red[3]) * (1.f / DIM);
  float d0 = v0 - mean, d1 = v1 - mean, d2 = v2 - mean, d3 = v3 - mean;
  float q = d0 * d0 + d1 * d1 + d2 * d2 + d3 * d3;
#pragma unroll
  for (int o = 32; o >= 1; o >>= 1) q += __shfl_xor(q, o);
  if ((tid & 63) == 0) red[4 + (tid >> 6)] = q;
  __syncthreads();
  float var = (red[4] + red[5] + red[6] + red[7]) * (1.f / DIM);
  float rstd = rsqrtf(var + LNEPS);
  yr[tid]       = f2bf(d0 * rstd * w[tid] + b[tid]);
  yr[tid + 256] = f2bf(d1 * rstd * w[tid + 256] + b[tid + 256]);
  yr[tid + 512] = f2bf(d2 * rstd * w[tid + 512] + b[tid + 512]);
  yr[tid + 768] = f2bf(d3 * rstd * w[tid + 768] + b[tid + 768]);
}

// ---------------- fused: h += bias + sum(partials); x = LN(h) bf16 ----------------
template <int NPART>
__global__ void reduce_ln(const float* __restrict__ part, const float* __restrict__ bias,
                          const float* __restrict__ lnw, const float* __restrict__ lnb,
                          float* __restrict__ h, short* __restrict__ x) {
  const long MN = (long)SEQ * DIM;
  int row = blockIdx.x, tid = threadIdx.x;
  long off = (long)row * DIM + tid * 4;
  fl4 hv = *(const fl4*)(h + off);
  fl4 bv = *(const fl4*)(bias + tid * 4);
  float v[4];
#pragma unroll
  for (int u = 0; u < 4; u++) v[u] = hv[u] + bv[u];
#pragma unroll
  for (int p = 0; p < NPART; p++) {
    fl4 pv = *(const fl4*)(part + (long)p * MN + off);
#pragma unroll
    for (int u = 0; u < 4; u++) v[u] += pv[u];
  }
  __shared__ float red[8];
  float s = v[0] + v[1] + v[2] + v[3];
#pragma unroll
  for (int o = 32; o >= 1; o >>= 1) s += __shfl_xor(s, o);
  if ((tid & 63) == 0) red[tid >> 6] = s;
  __syncthreads();
  float mean = (red[0] + red[1] + red[2] + red[3]) * (1.f / DIM);
  float d[4], q = 0.f;
#pragma unroll
  for (int u = 0; u < 4; u++) { d[u] = v[u] - mean; q += d[u] * d[u]; }
#pragma unroll
  for (int o = 32; o >= 1; o >>= 1) q += __shfl_xor(q, o);
  if ((tid & 63) == 0) red[4 + (tid >> 6)] = q;
  fl4 hw; hw[0] = v[0]; hw[1] = v[1]; hw[2] = v[2]; hw[3] = v[3];
  *(fl4*)(h + off) = hw;
  __syncthreads();
  float var = (red[4] + red[5] + red[6] + red[7]) * (1.f / DIM);
  float rstd = rsqrtf(var + LNEPS);
  fl4 w = *(const fl4*)(lnw + tid * 4);
  fl4 bb = *(const fl4*)(lnb + tid * 4);
  s16x4 o;
#pragma unroll
  for (int u = 0; u < 4; u++) o[u] = f2bf(d[u] * rstd * w[u] + bb[u]);
  *(s16x4*)(x + off) = o;
}

// ---------------- merged per-layer weight prep: 6 transposes + bias concat ----------------
struct Prep {
  const float *wq, *wk, *wv, *wo, *w1, *w2, *bq, *bk, *bv;
  short *qkvT, *woT, *w1T, *w2T;
  float* bias3;
};
__global__ void prep_kernel(Prep p) {
  int t = blockIdx.x;
  if (t >= 3072) {
    for (int k = threadIdx.x; k < QKVD; k += 256)
      p.bias3[k] = k < DIM ? p.bq[k] : (k < 2 * DIM ? p.bk[k - DIM] : p.bv[k - 2 * DIM]);
    return;
  }
  const float* in; short* out; int Kd, Nd, r0, c0;
  if (t < 1024) {
    int m = t >> 8, lt = t & 255;
    const float* srcs[4] = {p.wq, p.wk, p.wv, p.wo};
    short* dsts[4] = {p.qkvT, p.qkvT + (long)DIM * DIM, p.qkvT + (long)2 * DIM * DIM, p.woT};
    in = srcs[m]; out = dsts[m]; Kd = DIM; Nd = DIM;
    c0 = (lt & 15) * 64; r0 = (lt >> 4) * 64;
  } else if (t < 2048) {
    int lt = t - 1024; in = p.w1; out = p.w1T; Kd = DIM; Nd = FFN;
    c0 = (lt & 63) * 64; r0 = (lt >> 6) * 64;
  } else {
    int lt = t - 2048; in = p.w2; out = p.w2T; Kd = FFN; Nd = DIM;
    c0 = (lt & 15) * 64; r0 = (lt >> 4) * 64;
  }
  __shared__ float ts[64][65];
  int tid = threadIdx.x;
  int lr = tid >> 4, lc4 = (tid & 15) * 4;
#pragma unroll
  for (int i = 0; i < 4; i++) {
    fl4 v = *(const fl4*)(in + (long)(r0 + lr + i * 16) * Nd + c0 + lc4);
    ts[lr + i * 16][lc4] = v[0]; ts[lr + i * 16][lc4 + 1] = v[1];
    ts[lr + i * 16][lc4 + 2] = v[2]; ts[lr + i * 16][lc4 + 3] = v[3];
  }
  __syncthreads();
#pragma unroll
  for (int i = 0; i < 2; i++) {
    int oc = (tid >> 3) + i * 32, seg = tid & 7;
    bf16x8 o;
#pragma unroll
    for (int u = 0; u < 8; u++) o[u] = f2bf(ts[seg * 8 + u][oc]);
    *(bf16x8*)(out + (long)(c0 + oc) * Kd + r0 + seg * 8) = o;
  }
}

// ---------------- V transpose: qkv[s][2D+c] -> vt[c][s] ----------------
__global__ void transpose_v(const short* __restrict__ qkv, short* __restrict__ vt) {
  __shared__ short t[64][72];
  int s0 = blockIdx.x * 64, c0 = blockIdx.y * 64;
  int tid = threadIdx.x;
#pragma unroll
  for (int i = 0; i < 2; i++) {
    int ca = i * 256 + tid;
    int row = ca >> 3, cp = ca & 7;
    bf16x8 v = *(const bf16x8*)(qkv + (long)(s0 + row) * QKVD + 2 * DIM + c0 + cp * 8);
    *(bf16x8*)&t[row][cp * 8] = v;
  }
  __syncthreads();
#pragma unroll
  for (int i = 0; i < 2; i++) {
    int ca = i * 256 + tid;
    int crow = ca >> 3, sp = ca & 7;
    bf16x8 o;
#pragma unroll
    for (int u = 0; u < 8; u++) o[u] = t[sp * 8 + u][crow];
    *(bf16x8*)(vt + (long)(c0 + crow) * SEQ + s0 + sp * 8) = o;
  }
}

// ---------------- gemm_small: 64x128 tile, BK=32, 4 waves (QKV/proj/FFN2) ----------------
template <bool GELU, bool BIAS, bool OUTBF16, int KS, bool XCDSWZ>
__global__ __launch_bounds__(256, 4) void gemm_small(
    const short* __restrict__ A, const short* __restrict__ Bt,
    const float* __restrict__ bias, void* __restrict__ Cout, int N, int Kfull) {
  __shared__ short lds[3][(64 + 128) * 32];  // 3 x 12KB
  const int tid = threadIdx.x, wid = tid >> 6, lane = tid & 63;
  const int l16 = lane & 15, lg = lane >> 4;
  int bx = blockIdx.x, by = blockIdx.y;
  if (XCDSWZ) {
    int gx = gridDim.x, nwg = gx * gridDim.y;
    int flat = by * gx + bx;
    int nf = (flat & 7) * (nwg >> 3) + (flat >> 3);
    bx = nf % gx; by = nf / gx;
  }
  const long m0 = (long)bx * 64, n0 = (long)by * 128;
  const int K = Kfull / KS;
  const int kbase = blockIdx.z * K;
  const int NT = K / 32;
  const int wm = wid >> 1, wn = wid & 1;

#define STG(t, b)                                                               \
  {                                                                             \
    short* As_ = lds[b];                                                        \
    short* Bs_ = lds[b] + 64 * 32;                                              \
    int kk_ = kbase + (t) * 32;                                                 \
    {                                                                           \
      int row_ = tid >> 2, cp_ = tid & 3, c_ = cp_ ^ ((row_ >> 1) & 3);         \
      gload_lds16(A + (m0 + row_) * (long)Kfull + kk_ + c_ * 8,                 \
                  As_ + (wid * 64) * 8);                                        \
    }                                                                           \
    _Pragma("unroll")                                                           \
    for (int i_ = 0; i_ < 2; i_++) {                                            \
      int ca_ = i_ * 256 + tid;                                                 \
      int row_ = ca_ >> 2, cp_ = ca_ & 3, c_ = cp_ ^ ((row_ >> 1) & 3);         \
      gload_lds16(Bt + (long)(n0 + row_) * Kfull + kk_ + c_ * 8,                \
                  Bs_ + (i_ * 256 + wid * 64) * 8);                             \
    }                                                                           \
  }

  f32x4 acc[2][4] = {};
  STG(0, 0);
  STG(1, 1);
  asm volatile("s_waitcnt vmcnt(3)" ::: "memory");
  __builtin_amdgcn_s_barrier();
  __builtin_amdgcn_sched_barrier(0);

  for (int t = 0; t < NT; t++) {
    const int b = t % 3;
    if (t + 2 < NT) STG(t + 2, (t + 2) % 3);
    const short* As = lds[b];
    const short* Bs = lds[b] + 64 * 32;
    bf16x8 af[2], bfr[4];
#pragma unroll
    for (int m = 0; m < 2; m++) {
      int row = wm * 32 + m * 16 + l16;
      af[m] = *(const bf16x8*)((const char*)As + row * 64 + ((lg ^ ((row >> 1) & 3)) * 16));
    }
#pragma unroll
    for (int n = 0; n < 4; n++) {
      int row = wn * 64 + n * 16 + l16;
      bfr[n] = *(const bf16x8*)((const char*)Bs + row * 64 + ((lg ^ ((row >> 1) & 3)) * 16));
    }
    __builtin_amdgcn_s_setprio(1);
#pragma unroll
    for (int m = 0; m < 2; m++)
#pragma unroll
      for (int n = 0; n < 4; n++)
        acc[m][n] = __builtin_amdgcn_mfma_f32_16x16x32_bf16(af[m], bfr[n], acc[m][n], 0, 0, 0);
    __builtin_amdgcn_s_setprio(0);
    if (t + 2 < NT) {
      asm volatile("s_waitcnt vmcnt(3)" ::: "memory");
    } else if (t + 1 < NT) {
      asm volatile("s_waitcnt vmcnt(0)" ::: "memory");
    }
    if (t + 1 < NT) {
      __builtin_amdgcn_s_barrier();
      __builtin_amdgcn_sched_barrier(0);
    }
  }
#undef STG

  const int lr4 = lg * 4;
  if (KS == 1) {
#pragma unroll
    for (int m = 0; m < 2; m++)
#pragma unroll
      for (int n = 0; n < 4; n++)
#pragma unroll
        for (int r = 0; r < 4; r++) {
          long row = m0 + wm * 32 + m * 16 + lr4 + r;
          long col = n0 + wn * 64 + n * 16 + l16;
          float v = acc[m][n][r];
          if (BIAS) v += bias[col];
          if (GELU) v = 0.5f * v * (1.f + erff(v * 0.70710678118f));
          if (OUTBF16) ((short*)Cout)[row * (long)N + col] = f2bf(v);
          else ((float*)Cout)[row * (long)N + col] = v;
        }
  } else {
    long M = (long)gridDim.x * 64;
    float* P = (float*)Cout + (long)blockIdx.z * M * N;
#pragma unroll
    for (int m = 0; m < 2; m++)
#pragma unroll
      for (int n = 0; n < 4; n++)
#pragma unroll
        for (int r = 0; r < 4; r++) {
          long row = m0 + wm * 32 + m * 16 + lr4 + r;
          long col = n0 + wn * 64 + n * 16 + l16;
          P[row * (long)N + col] = acc[m][n][r];
        }
  }
}

// ---------------- gemm4: 128x128, BK=32, 3 blocks/CU (FFN1) ----------------
template <bool GELU, bool BIAS, bool OUTBF16, bool XCDSWZ>
__global__ __launch_bounds__(256, 3) void gemm4(
    const short* __restrict__ A, const short* __restrict__ Bt,
    const float* __restrict__ bias, void* __restrict__ Cout, int N, int Kfull) {
  __shared__ short lds[3][(128 + 128) * 32];  // 3 x 16KB
  const int tid = threadIdx.x, wid = tid >> 6, lane = tid & 63;
  const int l16 = lane & 15, lg = lane >> 4;
  int bx = blockIdx.x, by = blockIdx.y;
  if (XCDSWZ) {
    int gx = gridDim.x, nwg = gx * gridDim.y;
    int flat = by * gx + bx;
    int nf = (flat & 7) * (nwg >> 3) + (flat >> 3);
    bx = nf % gx; by = nf / gx;
  }
  const long m0 = (long)bx * 128, n0 = (long)by * 128;
  const int NT = Kfull / 32;
  const int wr = (wid >> 1) * 64, wc = (wid & 1) * 64;

#define STAGE4(t, b)                                                            \
  {                                                                             \
    short* As_ = lds[b];                                                        \
    short* Bs_ = lds[b] + 128 * 32;                                             \
    int kk_ = (t) * 32;                                                         \
    _Pragma("unroll")                                                           \
    for (int i_ = 0; i_ < 2; i_++) {                                            \
      int ca_ = i_ * 256 + tid;                                                 \
      int row_ = ca_ >> 2, cp_ = ca_ & 3, c_ = cp_ ^ ((row_ >> 1) & 3);         \
      gload_lds16(A + (m0 + row_) * (long)Kfull + kk_ + c_ * 8,                 \
                  As_ + (i_ * 256 + wid * 64) * 8);                             \
    }                                                                           \
    _Pragma("unroll")                                                           \
    for (int i_ = 0; i_ < 2; i_++) {                                            \
      int ca_ = i_ * 256 + tid;                                                 \
      int row_ = ca_ >> 2, cp_ = ca_ & 3, c_ = cp_ ^ ((row_ >> 1) & 3);         \
      gload_lds16(Bt + (long)(n0 + row_) * Kfull + kk_ + c_ * 8,                \
                  Bs_ + (i_ * 256 + wid * 64) * 8);                             \
    }                                                                           \
  }

  f32x4 acc[4][4] = {};
  STAGE4(0, 0);
  STAGE4(1, 1);
  asm volatile("s_waitcnt vmcnt(4)" ::: "memory");
  __builtin_amdgcn_s_barrier();
  __builtin_amdgcn_sched_barrier(0);

  for (int t = 0; t < NT; t++) {
    const int b = t % 3;
    if (t + 2 < NT) STAGE4(t + 2, (t + 2) % 3);
    const short* As = lds[b];
    const short* Bs = lds[b] + 128 * 32;
    bf16x8 af[4], bfr[4];
#pragma unroll
    for (int m = 0; m < 4; m++) {
      int row = wr + m * 16 + l16;
      af[m] = *(const bf16x8*)((const char*)As + row * 64 + ((lg ^ ((row >> 1) & 3)) * 16));
    }
#pragma unroll
    for (int n = 0; n < 4; n++) {
      int row = wc + n * 16 + l16;
      bfr[n] = *(const bf16x8*)((const char*)Bs + row * 64 + ((lg ^ ((row >> 1) & 3)) * 16));
    }
    __builtin_amdgcn_s_setprio(1);
#pragma unroll
    for (int m = 0; m < 4; m++)
#pragma unroll
      for (int n = 0; n < 4; n++)
        acc[m][n] = __builtin_amdgcn_mfma_f32_16x16x32_bf16(af[m], bfr[n], acc[m][n], 0, 0, 0);
    __builtin_amdgcn_s_setprio(0);
    if (t + 2 < NT) {
      asm volatile("s_waitcnt vmcnt(4)" ::: "memory");
    } else if (t + 1 < NT) {
      asm volatile("s_waitcnt vmcnt(0)" ::: "memory");
    }
    if (t + 1 < NT) {
      __builtin_amdgcn_s_barrier();
      __builtin_amdgcn_sched_barrier(0);
    }
  }
#undef STAGE4

  const int lr4 = lg * 4;
#pragma unroll
  for (int m = 0; m < 4; m++)
#pragma unroll
    for (int n = 0; n < 4; n++)
#pragma unroll
      for (int r = 0; r < 4; r++) {
        long row = m0 + wr + m * 16 + lr4 + r;
        long col = n0 + wc + n * 16 + l16;
        float v = acc[m][n][r];
        if (BIAS) v += bias[col];
        if (GELU) v = 0.5f * v * (1.f + erff(v * 0.70710678118f));
        if (OUTBF16) ((short*)Cout)[row * (long)N + col] = f2bf(v);
        else ((float*)Cout)[row * (long)N + col] = v;
      }
}

// ---------------- gemm256b v4: lm_head, fused cvt, two-deep B pipeline (R15) ----------------
__global__ __launch_bounds__(512, 4) void gemm256b(
    const short* __restrict__ A, const float* __restrict__ Bt,
    float* __restrict__ C, int N, int K) {
  __shared__ short lds[3][(256 + 128) * 32];  // 3 x 24KB
  const int tid = threadIdx.x, wid = tid >> 6, lane = tid & 63;
  const int l16 = lane & 15, lg = lane >> 4;
  int bx = blockIdx.x, by = blockIdx.y;
  {  // XCD bijective remap; nwg = 8*393 = 3144 (%8 == 0)
    int gx = gridDim.x, nwg = gx * gridDim.y;
    int flat = by * gx + bx;
    int nf = (flat & 7) * (nwg >> 3) + (flat >> 3);
    bx = nf % gx; by = nf / gx;
  }
  const long m0 = (long)bx * 256, n0 = (long)by * 128;
  const int NT = K / 32;  // 32 (even)
  const int wm = wid >> 1, wn = wid & 1;

  const int brow = tid >> 2, bcp = tid & 3;
  const int bc = bcp ^ ((brow >> 1) & 3);
  int browg = (int)n0 + brow;
  if (browg > N - 1) browg = N - 1;
  const float* bsrc = Bt + (long)browg * K + bc * 8;

  fl4 bgE0, bgE1, bgO0, bgO1;
#define BLOADE(t)                                                               \
  {                                                                             \
    const float* p_ = bsrc + (t) * 32;                                          \
    asm volatile("global_load_dwordx4 %0, %1, off" : "=v"(bgE0) : "v"(p_));     \
    asm volatile("global_load_dwordx4 %0, %1, off" : "=v"(bgE1) : "v"(p_ + 4)); \
  }
#define BLOADO(t)                                                               \
  {                                                                             \
    const float* p_ = bsrc + (t) * 32;                                          \
    asm volatile("global_load_dwordx4 %0, %1, off" : "=v"(bgO0) : "v"(p_));     \
    asm volatile("global_load_dwordx4 %0, %1, off" : "=v"(bgO1) : "v"(p_ + 4)); \
  }
#define BWRITEE(b)                                                              \
  {                                                                             \
    bf16x8 o_;                                                                  \
    _Pragma("unroll")                                                           \
    for (int u_ = 0; u_ < 4; u_++) {                                            \
      o_[u_] = f2bf(bgE0[u_]);                                                  \
      o_[4 + u_] = f2bf(bgE1[u_]);                                              \
    }                                                                           \
    *(bf16x8*)(lds[b] + 256 * 32 + tid * 8) = o_;                               \
  }
#define BWRITEO(b)                                                              \
  {                                                                             \
    bf16x8 o_;                                                                  \
    _Pragma("unroll")                                                           \
    for (int u_ = 0; u_ < 4; u_++) {                                            \
      o_[u_] = f2bf(bgO0[u_]);                                                  \
      o_[4 + u_] = f2bf(bgO1[u_]);                                              \
    }                                                                           \
    *(bf16x8*)(lds[b] + 256 * 32 + tid * 8) = o_;                               \
  }
#define SA2(t, b)                                                               \
  {                                                                             \
    _Pragma("unroll")                                                           \
    for (int i_ = 0; i_ < 2; i_++) {                                            \
      int ca_ = i_ * 512 + tid;                                                 \
      int row_ = ca_ >> 2, cp_ = ca_ & 3, c_ = cp_ ^ ((row_ >> 1) & 3);         \
      gload_lds16(A + (m0 + row_) * (long)K + (t) * 32 + c_ * 8,                \
                  lds[b] + (i_ * 512 + wid * 64) * 8);                          \
    }                                                                           \
  }
#define COMPUTE(b)                                                              \
  {                                                                             \
    const short* As = lds[b];                                                   \
    const short* Bs = lds[b] + 256 * 32;                                        \
    bf16x8 bfr[4];                                                              \
    _Pragma("unroll")                                                           \
    for (int n = 0; n < 4; n++) {                                               \
      int row = wn * 64 + n * 16 + l16;                                         \
      bfr[n] = *(const bf16x8*)((const char*)Bs + row * 64 +                    \
                                ((lg ^ ((row >> 1) & 3)) * 16));                \
    }                                                                           \
    __builtin_amdgcn_s_setprio(1);                                              \
    _Pragma("unroll")                                                           \
    for (int m = 0; m < 4; m++) {                                               \
      int row = wm * 64 + m * 16 + l16;                                         \
      bf16x8 af = *(const bf16x8*)((const char*)As + row * 64 +                 \
                                   ((lg ^ ((row >> 1) & 3)) * 16));             \
      _Pragma("unroll")                                                         \
      for (int n = 0; n < 4; n++)                                               \
        acc[m][n] = __builtin_amdgcn_mfma_f32_16x16x32_bf16(af, bfr[n],         \
                                                            acc[m][n], 0, 0, 0);\
    }                                                                           \
    __builtin_amdgcn_s_setprio(0);                                              \
  }
#define TAILSYNC(s)                                                             \
  {                                                                             \
    if ((s) + 3 < NT) {                                                         \
      asm volatile("s_waitcnt vmcnt(4)" ::: "memory");                          \
    } else if ((s) + 2 < NT) {                                                  \
      asm volatile("s_waitcnt vmcnt(2)" ::: "memory");                          \
    } else if ((s) + 1 < NT) {                                                  \
      asm volatile("s_waitcnt vmcnt(0)" ::: "memory");                          \
    }                                                                           \
    if ((s) + 1 < NT) {                                                         \
      asm volatile("s_waitcnt lgkmcnt(0)" ::: "memory");                        \
      __builtin_amdgcn_s_barrier();                                             \
      __builtin_amdgcn_sched_barrier(0);                                        \
    }                                                                           \
  }

  f32x4 acc[4][4] = {};
  BLOADE(0);
  asm volatile("s_waitcnt vmcnt(0)" ::: "memory");
  __builtin_amdgcn_sched_barrier(0);
  BWRITEE(0);
  BLOADO(1);
  SA2(0, 0);
  SA2(1, 1);
  if (2 < NT) BLOADE(2);
  asm volatile("s_waitcnt vmcnt(4)" ::: "memory");
  asm volatile("s_waitcnt lgkmcnt(0)" ::: "memory");
  __builtin_amdgcn_s_barrier();
  __builtin_amdgcn_sched_barrier(0);

  for (int t = 0; t < NT; t += 2) {
    {  // even step s = t
      if (t + 1 < NT) BWRITEO((t + 1) % 3);
      if (t + 3 < NT) BLOADO(t + 3);
      if (t + 2 < NT) SA2(t + 2, (t + 2) % 3);
      COMPUTE(t % 3);
      TAILSYNC(t);
    }
    if (t + 1 < NT) {  // odd step s = t+1
      if (t + 2 < NT) BWRITEE((t + 2) % 3);
      if (t + 4 < NT) BLOADE(t + 4);
      if (t + 3 < NT) SA2(t + 3, (t + 3) % 3);
      COMPUTE((t + 1) % 3);
      TAILSYNC(t + 1);
    }
  }
#undef TAILSYNC
#undef COMPUTE
#undef SA2
#undef BWRITEO
#undef BWRITEE
#undef BLOADO
#undef BLOADE

  const int lr4 = lg * 4;
#pragma unroll
  for (int m = 0; m < 4; m++)
#pragma unroll
    for (int n = 0; n < 4; n++)
#pragma unroll
      for (int r = 0; r < 4; r++) {
        long row = m0 + wm * 64 + m * 16 + lr4 + r;
        long col = n0 + wn * 64 + n * 16 + l16;
        if (col < N) C[row * (long)N + col] = acc[m][n][r];
      }
}

// ---------------- MFMA flash attention, KVBLK=128, dbuf staging + setprio ----------------
__global__ __launch_bounds__(256) void attn_mfma(const short* __restrict__ qkv,
                                                 const short* __restrict__ vtg,
                                                 short* __restrict__ Oa) {
  int hh = blockIdx.x, qb = blockIdx.y;
  int q0 = qb * 64;
  int tid = threadIdx.x, wv = tid >> 6, lane = tid & 63;
  int l16 = lane & 15, lg = lane >> 4;
  int hcol = hh * 64;
  __shared__ short Ks[2][KVB * 64];
  __shared__ short Vt[2][64 * KVB];
  __shared__ short Pl[4][16 * KVB];

  bf16x8 qf[2];
  {
    const short* qrow = qkv + (long)(q0 + wv * 16 + l16) * QKVD + hcol;
#pragma unroll
    for (int dc = 0; dc < 2; dc++) {
      bf16x8 t = *(const bf16x8*)(qrow + dc * 32 + lg * 8);
#pragma unroll
      for (int j = 0; j < 8; j++) t[j] = f2bf(bf2f(t[j]) * 0.125f);
      qf[dc] = t;
    }
  }
  f32x4 of[4] = {};
  float mrun[4], lrun[4];
#pragma unroll
  for (int r = 0; r < 4; r++) { mrun[r] = -3e38f; lrun[r] = 0.f; }

#define STAGEKV(kt_, b_)                                                        \
  {                                                                             \
    int k0_ = (kt_) * KVB;                                                      \
    _Pragma("unroll")                                                           \
    for (int i = 0; i < 4; i++) {                                               \
      int ca = i * 256 + tid;                                                   \
      int row = ca >> 3, cp = ca & 7, c = cp ^ (row & 7);                       \
      gload_lds16(qkv + (long)(k0_ + row) * QKVD + DIM + hcol + c * 8,          \
                  (short*)Ks[b_] + (i * 256 + wv * 64) * 8);                    \
    }                                                                           \
    _Pragma("unroll")                                                           \
    for (int i = 0; i < 4; i++) {                                               \
      int ca = i * 256 + tid;                                                   \
      int row = ca >> 4, cp = ca & 15, c = cp ^ (row & 7);                      \
      gload_lds16(vtg + (long)(hcol + row) * SEQ + k0_ + c * 8,                 \
                  (short*)Vt[b_] + (i * 256 + wv * 64) * 8);                    \
    }                                                                           \
  }

  int nt = qb / 2 + 1;
  STAGEKV(0, 0);
  asm volatile("s_waitcnt vmcnt(0)" ::: "memory");
  __builtin_amdgcn_s_barrier();

  for (int kt = 0; kt < nt; kt++) {
    const int cur = kt & 1;
    if (kt + 1 < nt) STAGEKV(kt + 1, cur ^ 1);
    int k0 = kt * KVB;

    f32x4 sacc[8] = {};
    __builtin_amdgcn_s_setprio(1);
#pragma unroll
    for (int kc = 0; kc < 8; kc++) {
      int row = kc * 16 + l16;
#pragma unroll
      for (int dc = 0; dc < 2; dc++) {
        bf16x8 kf = *(const bf16x8*)((const char*)Ks[cur] + row * 128 + (((dc * 4 + lg) ^ (row & 7)) * 16));
        sacc[kc] = __builtin_amdgcn_mfma_f32_16x16x32_bf16(qf[dc], kf, sacc[kc], 0, 0, 0);
      }
    }
    __builtin_amdgcn_s_setprio(0);

    float sv[8][4], pf[8][4];
#pragma unroll
    for (int kc = 0; kc < 8; kc++)
#pragma unroll
      for (int r = 0; r < 4; r++) sv[kc][r] = sacc[kc][r];
    if (kt == nt - 1) {
#pragma unroll
      for (int kc = 0; kc < 8; kc++)
#pragma unroll
        for (int r = 0; r < 4; r++) {
          int kg = k0 + kc * 16 + l16;
          int rg = q0 + wv * 16 + lg * 4 + r;
          if (kg > rg) sv[kc][r] = -3e38f;
        }
    }
    float corr[4];
#pragma unroll
    for (int r = 0; r < 4; r++) {
      float m01 = fmaxf(sv[0][r], sv[1][r]), m23 = fmaxf(sv[2][r], sv[3][r]);
      float m45 = fmaxf(sv[4][r], sv[5][r]), m67 = fmaxf(sv[6][r], sv[7][r]);
      float mt = fmaxf(fmaxf(m01, m23), fmaxf(m45, m67));
#pragma unroll
      for (int o = 8; o >= 1; o >>= 1) mt = fmaxf(mt, __shfl_xor(mt, o));
      float mn = fmaxf(mrun[r], mt);
      corr[r] = __expf(mrun[r] - mn);
      mrun[r] = mn;
      float ps = 0.f;
#pragma unroll
      for (int kc = 0; kc < 8; kc++) {
        float p = __expf(sv[kc][r] - mn);
        pf[kc][r] = p;
        ps += p;
      }
#pragma unroll
      for (int o = 8; o >= 1; o >>= 1) ps += __shfl_xor(ps, o);
      lrun[r] = lrun[r] * corr[r] + ps;
    }
#pragma unroll
    for (int c = 0; c < 4; c++)
#pragma unroll
      for (int r = 0; r < 4; r++) of[c][r] *= corr[r];
#pragma unroll
    for (int kc = 0; kc < 8; kc++)
#pragma unroll
      for (int r = 0; r < 4; r++) {
        int row = lg * 4 + r, col = kc * 16 + l16;
        int chunk = col >> 3;
        *(short*)((char*)Pl[wv] + row * 256 + ((chunk ^ (row & 7)) * 16) + (col & 7) * 2) = f2bf(pf[kc][r]);
      }
    bf16x8 pfr[4];
#pragma unroll
    for (int kc2 = 0; kc2 < 4; kc2++) {
      int cl = kc2 * 4 + lg;
      pfr[kc2] = *(const bf16x8*)((const char*)Pl[wv] + l16 * 256 + ((cl ^ (l16 & 7)) * 16));
    }
    __builtin_amdgcn_s_setprio(1);
#pragma unroll
    for (int c = 0; c < 4; c++)
#pragma unroll
      for (int kc2 = 0; kc2 < 4; kc2++) {
        int vrow = c * 16 + l16;
        int cl = kc2 * 4 + lg;
        bf16x8 vf = *(const bf16x8*)((const char*)Vt[cur] + vrow * 256 + ((cl ^ (vrow & 7)) * 16));
        of[c] = __builtin_amdgcn_mfma_f32_16x16x32_bf16(pfr[kc2], vf, of[c], 0, 0, 0);
      }
    __builtin_amdgcn_s_setprio(0);
    if (kt + 1 < nt) {
      asm volatile("s_waitcnt vmcnt(0)" ::: "memory");
      __builtin_amdgcn_s_barrier();
      __builtin_amdgcn_sched_barrier(0);
    }
  }
#undef STAGEKV
#pragma unroll
  for (int c = 0; c < 4; c++)
#pragma unroll
    for (int r = 0; r < 4; r++) {
      int rowg = q0 + wv * 16 + lg * 4 + r;
      int colg = hcol + c * 16 + l16;
      Oa[(long)rowg * DIM + colg] = f2bf(of[c][r] / lrun[r]);
    }
}

// ---------------- orchestration ----------------
extern "C" void kernel_launch(void* const* d_in, const int* in_sizes, int n_in,
                              void* d_out, int out_size, void* d_ws, size_t ws_size,
                              hipStream_t stream) {
  const int* ids = (const int*)d_in[0];
  const float* tok = (const float*)d_in[1];
  const float* pos = (const float*)d_in[2];
  const float* Wq = (const float*)d_in[3];
  const float* bq = (const float*)d_in[4];
  const float* Wk = (const float*)d_in[5];
  const float* bk = (const float*)d_in[6];
  const float* Wv = (const float*)d_in[7];
  const float* bv = (const float*)d_in[8];
  const float* Wo = (const float*)d_in[9];
  const float* bo = (const float*)d_in[10];
  const float* W1 = (const float*)d_in[11];
  const float* b1 = (const float*)d_in[12];
  const float* W2 = (const float*)d_in[13];
  const float* b2 = (const float*)d_in[14];
  const float* ln1w = (const float*)d_in[15];
  const float* ln1b = (const float*)d_in[16];
  const float* ln2w = (const float*)d_in[17];
  const float* ln2b = (const float*)d_in[18];
  const float* lnfw = (const float*)d_in[19];
  const float* lnfb = (const float*)d_in[20];
  const float* lmh = (const float*)d_in[21];
  float* out = (float*)d_out;

  char* wsb = (char*)d_ws;
  float* h = (float*)wsb;                           // 8 MB fp32 residual
  short* x = (short*)(wsb + 8388608);               // 4 MB bf16 LN out
  char* big = wsb + 8388608 + 4194304;
  short* qkv  = (short*)big;                        // 12 MB   [S][3072]
  short* a    = (short*)(big + 12582912);           // 4 MB    [S][1024]
  short* vt   = (short*)(big + 16777216);           // 4 MB    [1024][S]
  short* fbuf = (short*)(big + 20971520);           // 16 MB   [S][4096]
  float* pproj = (float*)fbuf;                      // proj partials: 2x8MB (fbuf free then)
  char* wdyn = big + 37748736;
  short* wqkvT = (short*)wdyn;                      // 6 MB  [3072][1024]
  short* woT   = (short*)(wdyn + 6291456);          // 2 MB  [1024][1024]
  short* w1T   = (short*)(wdyn + 8388608);          // 8 MB  [4096][1024]
  short* w2T   = (short*)(wdyn + 16777216);         // 8 MB  [1024][4096]
  float* bias3 = (float*)(wdyn + 25165824);         // 12 KB
  float* pffn2 = (float*)(wsb + 79691776);          // 4x8MB at 76MB (ends 108MB)

  embed_kernel<<<(SEQ * DIM + 255) / 256, 256, 0, stream>>>(ids, tok, pos, h);
  ln_kernel<<<SEQ, 256, 0, stream>>>(h, ln1w, ln1b, x);  // layer 0 ln1

  dim3 gQKV(SEQ / 64, QKVD / 128);                  // 32 x 24 = 768
  dim3 gPROJ(SEQ / 64, DIM / 128, 2);               // 32 x 8 x 2 = 512
  dim3 gFFN1(SEQ / 128, FFN / 128);                 // 16 x 32 = 512
  dim3 gFFN2(SEQ / 64, DIM / 128, 4);               // 32 x 8 x 4 = 1024 (100% fill)
  dim3 gV(SEQ / 256, (VOCAB + 127) / 128);          // 8 x 393 = 3144 (%8==0)

  for (int l = 0; l < NLAYER; l++) {
    Prep p;
    p.wq = Wq + (long)l * DIM * DIM; p.wk = Wk + (long)l * DIM * DIM;
    p.wv = Wv + (long)l * DIM * DIM; p.wo = Wo + (long)l * DIM * DIM;
    p.w1 = W1 + (long)l * DIM * FFN; p.w2 = W2 + (long)l * FFN * DIM;
    p.bq = bq + (long)l * DIM; p.bk = bk + (long)l * DIM; p.bv = bv + (long)l * DIM;
    p.qkvT = wqkvT; p.woT = woT; p.w1T = w1T; p.w2T = w2T; p.bias3 = bias3;
    prep_kernel<<<3073, 256, 0, stream>>>(p);

    gemm_small<false, true, true, 1, true><<<gQKV, 256, 0, stream>>>(x, wqkvT, bias3, qkv, QKVD, DIM);
    transpose_v<<<dim3(SEQ / 64, DIM / 64), 256, 0, stream>>>(qkv, vt);
    attn_mfma<<<dim3(NHEAD, SEQ / 64), 256, 0, stream>>>(qkv, vt, a);
    gemm_small<false, false, false, 2, true><<<gPROJ, 256, 0, stream>>>(a, woT, nullptr, pproj, DIM, DIM);
    reduce_ln<2><<<SEQ, 256, 0, stream>>>(pproj, bo + (long)l * DIM,
                                          ln2w + (long)l * DIM, ln2b + (long)l * DIM, h, x);
    gemm4<true, true, true, true><<<gFFN1, 256, 0, stream>>>(x, w1T, b1 + (long)l * FFN, fbuf, FFN, DIM);
    gemm_small<false, false, false, 4, true><<<gFFN2, 256, 0, stream>>>(fbuf, w2T, nullptr, pffn2, DIM, FFN);
    const float* nw = (l < NLAYER - 1) ? ln1w + (long)(l + 1) * DIM : lnfw;
    const float* nb = (l < NLAYER - 1) ? ln1b + (long)(l + 1) * DIM : lnfb;
    reduce_ln<4><<<SEQ, 256, 0, stream>>>(pffn2, b2 + (long)l * DIM, nw, nb, h, x);
  }

  gemm256b<<<gV, 512, 0, stream>>>(x, lmh, out, VOCAB, DIM);
}

// Round 17
// 1081.567 us; speedup vs baseline: 1.0164x; 1.0164x over previous
//
#include <hip/hip_runtime.h>
#include <math.h>
#include <stdint.h>

// GPT fwd, L=4 D=1024 H=16 HS=64 F=4096 V=50257 S=2048.
// Round 17: revert to R15 config (best measured, 1086.9 us): FFN2 split-K
// back to 2 (NT=16; split-4's NT=8 spent half the pipeline in ramp and
// doubled partial traffic). All kernels byte-identical to R15-verified.

#define SEQ 2048
#define DIM 1024
#define NHEAD 16
#define FFN 4096
#define VOCAB 50257
#define NLAYER 4
#define LNEPS 1e-5f
#define QKVD 3072
#define KVB 128

using bf16x8 = __attribute__((ext_vector_type(8))) short;
using s16x4  = __attribute__((ext_vector_type(4))) short;
using f32x4  = __attribute__((ext_vector_type(4))) float;
using fl4    = __attribute__((ext_vector_type(4))) float;

static __device__ __forceinline__ short f2bf(float f) {
  uint32_t u = __float_as_uint(f);
  u = (u + 0x7fffu + ((u >> 16) & 1u)) >> 16;
  return (short)u;
}
static __device__ __forceinline__ float bf2f(short s) {
  return __uint_as_float(((uint32_t)(uint16_t)s) << 16);
}
static __device__ __forceinline__ void gload_lds16(const void* g, void* l) {
  __builtin_amdgcn_global_load_lds((const __attribute__((address_space(1))) void*)g,
                                   (__attribute__((address_space(3))) void*)l, 16, 0, 0);
}

// ---------------- embedding (fp32 h) ----------------
__global__ void embed_kernel(const int* __restrict__ ids,
                             const float* __restrict__ tok,
                             const float* __restrict__ pos,
                             float* __restrict__ h) {
  int i = blockIdx.x * blockDim.x + threadIdx.x;
  if (i < SEQ * DIM) {
    int s = i / DIM, d = i % DIM;
    h[i] = tok[(long)ids[s] * DIM + d] + pos[i];
  }
}

// ---------------- layernorm: fp32 in -> bf16 out (layer0 ln1 only) ----------------
__global__ void ln_kernel(const float* __restrict__ x, const float* __restrict__ w,
                          const float* __restrict__ b, short* __restrict__ y) {
  int row = blockIdx.x;
  const float* xr = x + (long)row * DIM;
  short* yr = y + (long)row * DIM;
  int tid = threadIdx.x;
  float v0 = xr[tid], v1 = xr[tid + 256], v2 = xr[tid + 512], v3 = xr[tid + 768];
  __shared__ float red[8];
  float s = v0 + v1 + v2 + v3;
#pragma unroll
  for (int o = 32; o >= 1; o >>= 1) s += __shfl_xor(s, o);
  if ((tid & 63) == 0) red[tid >> 6] = s;
  __syncthreads();
  float mean = (red[0] + red[1] + red[2] + red[3]) * (1.f / DIM);
  float d0 = v0 - mean, d1 = v1 - mean, d2 = v2 - mean, d3 = v3 - mean;
  float q = d0 * d0 + d1 * d1 + d2 * d2 + d3 * d3;
#pragma unroll
  for (int o = 32; o >= 1; o >>= 1) q += __shfl_xor(q, o);
  if ((tid & 63) == 0) red[4 + (tid >> 6)] = q;
  __syncthreads();
  float var = (red[4] + red[5] + red[6] + red[7]) * (1.f / DIM);
  float rstd = rsqrtf(var + LNEPS);
  yr[tid]       = f2bf(d0 * rstd * w[tid] + b[tid]);
  yr[tid + 256] = f2bf(d1 * rstd * w[tid + 256] + b[tid + 256]);
  yr[tid + 512] = f2bf(d2 * rstd * w[tid + 512] + b[tid + 512]);
  yr[tid + 768] = f2bf(d3 * rstd * w[tid + 768] + b[tid + 768]);
}

// ---------------- fused: h += bias + sum(partials); x = LN(h) bf16 ----------------
template <int NPART>
__global__ void reduce_ln(const float* __restrict__ part, const float* __restrict__ bias,
                          const float* __restrict__ lnw, const float* __restrict__ lnb,
                          float* __restrict__ h, short* __restrict__ x) {
  const long MN = (long)SEQ * DIM;
  int row = blockIdx.x, tid = threadIdx.x;
  long off = (long)row * DIM + tid * 4;
  fl4 hv = *(const fl4*)(h + off);
  fl4 bv = *(const fl4*)(bias + tid * 4);
  float v[4];
#pragma unroll
  for (int u = 0; u < 4; u++) v[u] = hv[u] + bv[u];
#pragma unroll
  for (int p = 0; p < NPART; p++) {
    fl4 pv = *(const fl4*)(part + (long)p * MN + off);
#pragma unroll
    for (int u = 0; u < 4; u++) v[u] += pv[u];
  }
  __shared__ float red[8];
  float s = v[0] + v[1] + v[2] + v[3];
#pragma unroll
  for (int o = 32; o >= 1; o >>= 1) s += __shfl_xor(s, o);
  if ((tid & 63) == 0) red[tid >> 6] = s;
  __syncthreads();
  float mean = (red[0] + red[1] + red[2] + red[3]) * (1.f / DIM);
  float d[4], q = 0.f;
#pragma unroll
  for (int u = 0; u < 4; u++) { d[u] = v[u] - mean; q += d[u] * d[u]; }
#pragma unroll
  for (int o = 32; o >= 1; o >>= 1) q += __shfl_xor(q, o);
  if ((tid & 63) == 0) red[4 + (tid >> 6)] = q;
  fl4 hw; hw[0] = v[0]; hw[1] = v[1]; hw[2] = v[2]; hw[3] = v[3];
  *(fl4*)(h + off) = hw;
  __syncthreads();
  float var = (red[4] + red[5] + red[6] + red[7]) * (1.f / DIM);
  float rstd = rsqrtf(var + LNEPS);
  fl4 w = *(const fl4*)(lnw + tid * 4);
  fl4 bb = *(const fl4*)(lnb + tid * 4);
  s16x4 o;
#pragma unroll
  for (int u = 0; u < 4; u++) o[u] = f2bf(d[u] * rstd * w[u] + bb[u]);
  *(s16x4*)(x + off) = o;
}

// ---------------- merged per-layer weight prep: 6 transposes + bias concat ----------------
struct Prep {
  const float *wq, *wk, *wv, *wo, *w1, *w2, *bq, *bk, *bv;
  short *qkvT, *woT, *w1T, *w2T;
  float* bias3;
};
__global__ void prep_kernel(Prep p) {
  int t = blockIdx.x;
  if (t >= 3072) {
    for (int k = threadIdx.x; k < QKVD; k += 256)
      p.bias3[k] = k < DIM ? p.bq[k] : (k < 2 * DIM ? p.bk[k - DIM] : p.bv[k - 2 * DIM]);
    return;
  }
  const float* in; short* out; int Kd, Nd, r0, c0;
  if (t < 1024) {
    int m = t >> 8, lt = t & 255;
    const float* srcs[4] = {p.wq, p.wk, p.wv, p.wo};
    short* dsts[4] = {p.qkvT, p.qkvT + (long)DIM * DIM, p.qkvT + (long)2 * DIM * DIM, p.woT};
    in = srcs[m]; out = dsts[m]; Kd = DIM; Nd = DIM;
    c0 = (lt & 15) * 64; r0 = (lt >> 4) * 64;
  } else if (t < 2048) {
    int lt = t - 1024; in = p.w1; out = p.w1T; Kd = DIM; Nd = FFN;
    c0 = (lt & 63) * 64; r0 = (lt >> 6) * 64;
  } else {
    int lt = t - 2048; in = p.w2; out = p.w2T; Kd = FFN; Nd = DIM;
    c0 = (lt & 15) * 64; r0 = (lt >> 4) * 64;
  }
  __shared__ float ts[64][65];
  int tid = threadIdx.x;
  int lr = tid >> 4, lc4 = (tid & 15) * 4;
#pragma unroll
  for (int i = 0; i < 4; i++) {
    fl4 v = *(const fl4*)(in + (long)(r0 + lr + i * 16) * Nd + c0 + lc4);
    ts[lr + i * 16][lc4] = v[0]; ts[lr + i * 16][lc4 + 1] = v[1];
    ts[lr + i * 16][lc4 + 2] = v[2]; ts[lr + i * 16][lc4 + 3] = v[3];
  }
  __syncthreads();
#pragma unroll
  for (int i = 0; i < 2; i++) {
    int oc = (tid >> 3) + i * 32, seg = tid & 7;
    bf16x8 o;
#pragma unroll
    for (int u = 0; u < 8; u++) o[u] = f2bf(ts[seg * 8 + u][oc]);
    *(bf16x8*)(out + (long)(c0 + oc) * Kd + r0 + seg * 8) = o;
  }
}

// ---------------- V transpose: qkv[s][2D+c] -> vt[c][s] ----------------
__global__ void transpose_v(const short* __restrict__ qkv, short* __restrict__ vt) {
  __shared__ short t[64][72];
  int s0 = blockIdx.x * 64, c0 = blockIdx.y * 64;
  int tid = threadIdx.x;
#pragma unroll
  for (int i = 0; i < 2; i++) {
    int ca = i * 256 + tid;
    int row = ca >> 3, cp = ca & 7;
    bf16x8 v = *(const bf16x8*)(qkv + (long)(s0 + row) * QKVD + 2 * DIM + c0 + cp * 8);
    *(bf16x8*)&t[row][cp * 8] = v;
  }
  __syncthreads();
#pragma unroll
  for (int i = 0; i < 2; i++) {
    int ca = i * 256 + tid;
    int crow = ca >> 3, sp = ca & 7;
    bf16x8 o;
#pragma unroll
    for (int u = 0; u < 8; u++) o[u] = t[sp * 8 + u][crow];
    *(bf16x8*)(vt + (long)(c0 + crow) * SEQ + s0 + sp * 8) = o;
  }
}

// ---------------- gemm_small: 64x128 tile, BK=32, 4 waves (QKV/proj/FFN2) ----------------
template <bool GELU, bool BIAS, bool OUTBF16, int KS, bool XCDSWZ>
__global__ __launch_bounds__(256, 4) void gemm_small(
    const short* __restrict__ A, const short* __restrict__ Bt,
    const float* __restrict__ bias, void* __restrict__ Cout, int N, int Kfull) {
  __shared__ short lds[3][(64 + 128) * 32];  // 3 x 12KB
  const int tid = threadIdx.x, wid = tid >> 6, lane = tid & 63;
  const int l16 = lane & 15, lg = lane >> 4;
  int bx = blockIdx.x, by = blockIdx.y;
  if (XCDSWZ) {
    int gx = gridDim.x, nwg = gx * gridDim.y;
    int flat = by * gx + bx;
    int nf = (flat & 7) * (nwg >> 3) + (flat >> 3);
    bx = nf % gx; by = nf / gx;
  }
  const long m0 = (long)bx * 64, n0 = (long)by * 128;
  const int K = Kfull / KS;
  const int kbase = blockIdx.z * K;
  const int NT = K / 32;
  const int wm = wid >> 1, wn = wid & 1;

#define STG(t, b)                                                               \
  {                                                                             \
    short* As_ = lds[b];                                                        \
    short* Bs_ = lds[b] + 64 * 32;                                              \
    int kk_ = kbase + (t) * 32;                                                 \
    {                                                                           \
      int row_ = tid >> 2, cp_ = tid & 3, c_ = cp_ ^ ((row_ >> 1) & 3);         \
      gload_lds16(A + (m0 + row_) * (long)Kfull + kk_ + c_ * 8,                 \
                  As_ + (wid * 64) * 8);                                        \
    }                                                                           \
    _Pragma("unroll")                                                           \
    for (int i_ = 0; i_ < 2; i_++) {                                            \
      int ca_ = i_ * 256 + tid;                                                 \
      int row_ = ca_ >> 2, cp_ = ca_ & 3, c_ = cp_ ^ ((row_ >> 1) & 3);         \
      gload_lds16(Bt + (long)(n0 + row_) * Kfull + kk_ + c_ * 8,                \
                  Bs_ + (i_ * 256 + wid * 64) * 8);                             \
    }                                                                           \
  }

  f32x4 acc[2][4] = {};
  STG(0, 0);
  STG(1, 1);
  asm volatile("s_waitcnt vmcnt(3)" ::: "memory");
  __builtin_amdgcn_s_barrier();
  __builtin_amdgcn_sched_barrier(0);

  for (int t = 0; t < NT; t++) {
    const int b = t % 3;
    if (t + 2 < NT) STG(t + 2, (t + 2) % 3);
    const short* As = lds[b];
    const short* Bs = lds[b] + 64 * 32;
    bf16x8 af[2], bfr[4];
#pragma unroll
    for (int m = 0; m < 2; m++) {
      int row = wm * 32 + m * 16 + l16;
      af[m] = *(const bf16x8*)((const char*)As + row * 64 + ((lg ^ ((row >> 1) & 3)) * 16));
    }
#pragma unroll
    for (int n = 0; n < 4; n++) {
      int row = wn * 64 + n * 16 + l16;
      bfr[n] = *(const bf16x8*)((const char*)Bs + row * 64 + ((lg ^ ((row >> 1) & 3)) * 16));
    }
    __builtin_amdgcn_s_setprio(1);
#pragma unroll
    for (int m = 0; m < 2; m++)
#pragma unroll
      for (int n = 0; n < 4; n++)
        acc[m][n] = __builtin_amdgcn_mfma_f32_16x16x32_bf16(af[m], bfr[n], acc[m][n], 0, 0, 0);
    __builtin_amdgcn_s_setprio(0);
    if (t + 2 < NT) {
      asm volatile("s_waitcnt vmcnt(3)" ::: "memory");
    } else if (t + 1 < NT) {
      asm volatile("s_waitcnt vmcnt(0)" ::: "memory");
    }
    if (t + 1 < NT) {
      __builtin_amdgcn_s_barrier();
      __builtin_amdgcn_sched_barrier(0);
    }
  }
#undef STG

  const int lr4 = lg * 4;
  if (KS == 1) {
#pragma unroll
    for (int m = 0; m < 2; m++)
#pragma unroll
      for (int n = 0; n < 4; n++)
#pragma unroll
        for (int r = 0; r < 4; r++) {
          long row = m0 + wm * 32 + m * 16 + lr4 + r;
          long col = n0 + wn * 64 + n * 16 + l16;
          float v = acc[m][n][r];
          if (BIAS) v += bias[col];
          if (GELU) v = 0.5f * v * (1.f + erff(v * 0.70710678118f));
          if (OUTBF16) ((short*)Cout)[row * (long)N + col] = f2bf(v);
          else ((float*)Cout)[row * (long)N + col] = v;
        }
  } else {
    long M = (long)gridDim.x * 64;
    float* P = (float*)Cout + (long)blockIdx.z * M * N;
#pragma unroll
    for (int m = 0; m < 2; m++)
#pragma unroll
      for (int n = 0; n < 4; n++)
#pragma unroll
        for (int r = 0; r < 4; r++) {
          long row = m0 + wm * 32 + m * 16 + lr4 + r;
          long col = n0 + wn * 64 + n * 16 + l16;
          P[row * (long)N + col] = acc[m][n][r];
        }
  }
}

// ---------------- gemm4: 128x128, BK=32, 3 blocks/CU (FFN1) ----------------
template <bool GELU, bool BIAS, bool OUTBF16, bool XCDSWZ>
__global__ __launch_bounds__(256, 3) void gemm4(
    const short* __restrict__ A, const short* __restrict__ Bt,
    const float* __restrict__ bias, void* __restrict__ Cout, int N, int Kfull) {
  __shared__ short lds[3][(128 + 128) * 32];  // 3 x 16KB
  const int tid = threadIdx.x, wid = tid >> 6, lane = tid & 63;
  const int l16 = lane & 15, lg = lane >> 4;
  int bx = blockIdx.x, by = blockIdx.y;
  if (XCDSWZ) {
    int gx = gridDim.x, nwg = gx * gridDim.y;
    int flat = by * gx + bx;
    int nf = (flat & 7) * (nwg >> 3) + (flat >> 3);
    bx = nf % gx; by = nf / gx;
  }
  const long m0 = (long)bx * 128, n0 = (long)by * 128;
  const int NT = Kfull / 32;
  const int wr = (wid >> 1) * 64, wc = (wid & 1) * 64;

#define STAGE4(t, b)                                                            \
  {                                                                             \
    short* As_ = lds[b];                                                        \
    short* Bs_ = lds[b] + 128 * 32;                                             \
    int kk_ = (t) * 32;                                                         \
    _Pragma("unroll")                                                           \
    for (int i_ = 0; i_ < 2; i_++) {                                            \
      int ca_ = i_ * 256 + tid;                                                 \
      int row_ = ca_ >> 2, cp_ = ca_ & 3, c_ = cp_ ^ ((row_ >> 1) & 3);         \
      gload_lds16(A + (m0 + row_) * (long)Kfull + kk_ + c_ * 8,                 \
                  As_ + (i_ * 256 + wid * 64) * 8);                             \
    }                                                                           \
    _Pragma("unroll")                                                           \
    for (int i_ = 0; i_ < 2; i_++) {                                            \
      int ca_ = i_ * 256 + tid;                                                 \
      int row_ = ca_ >> 2, cp_ = ca_ & 3, c_ = cp_ ^ ((row_ >> 1) & 3);         \
      gload_lds16(Bt + (long)(n0 + row_) * Kfull + kk_ + c_ * 8,                \
                  Bs_ + (i_ * 256 + wid * 64) * 8);                             \
    }                                                                           \
  }

  f32x4 acc[4][4] = {};
  STAGE4(0, 0);
  STAGE4(1, 1);
  asm volatile("s_waitcnt vmcnt(4)" ::: "memory");
  __builtin_amdgcn_s_barrier();
  __builtin_amdgcn_sched_barrier(0);

  for (int t = 0; t < NT; t++) {
    const int b = t % 3;
    if (t + 2 < NT) STAGE4(t + 2, (t + 2) % 3);
    const short* As = lds[b];
    const short* Bs = lds[b] + 128 * 32;
    bf16x8 af[4], bfr[4];
#pragma unroll
    for (int m = 0; m < 4; m++) {
      int row = wr + m * 16 + l16;
      af[m] = *(const bf16x8*)((const char*)As + row * 64 + ((lg ^ ((row >> 1) & 3)) * 16));
    }
#pragma unroll
    for (int n = 0; n < 4; n++) {
      int row = wc + n * 16 + l16;
      bfr[n] = *(const bf16x8*)((const char*)Bs + row * 64 + ((lg ^ ((row >> 1) & 3)) * 16));
    }
    __builtin_amdgcn_s_setprio(1);
#pragma unroll
    for (int m = 0; m < 4; m++)
#pragma unroll
      for (int n = 0; n < 4; n++)
        acc[m][n] = __builtin_amdgcn_mfma_f32_16x16x32_bf16(af[m], bfr[n], acc[m][n], 0, 0, 0);
    __builtin_amdgcn_s_setprio(0);
    if (t + 2 < NT) {
      asm volatile("s_waitcnt vmcnt(4)" ::: "memory");
    } else if (t + 1 < NT) {
      asm volatile("s_waitcnt vmcnt(0)" ::: "memory");
    }
    if (t + 1 < NT) {
      __builtin_amdgcn_s_barrier();
      __builtin_amdgcn_sched_barrier(0);
    }
  }
#undef STAGE4

  const int lr4 = lg * 4;
#pragma unroll
  for (int m = 0; m < 4; m++)
#pragma unroll
    for (int n = 0; n < 4; n++)
#pragma unroll
      for (int r = 0; r < 4; r++) {
        long row = m0 + wr + m * 16 + lr4 + r;
        long col = n0 + wc + n * 16 + l16;
        float v = acc[m][n][r];
        if (BIAS) v += bias[col];
        if (GELU) v = 0.5f * v * (1.f + erff(v * 0.70710678118f));
        if (OUTBF16) ((short*)Cout)[row * (long)N + col] = f2bf(v);
        else ((float*)Cout)[row * (long)N + col] = v;
      }
}

// ---------------- gemm256b v4: lm_head, fused cvt, two-deep B pipeline (R15) ----------------
__global__ __launch_bounds__(512, 4) void gemm256b(
    const short* __restrict__ A, const float* __restrict__ Bt,
    float* __restrict__ C, int N, int K) {
  __shared__ short lds[3][(256 + 128) * 32];  // 3 x 24KB
  const int tid = threadIdx.x, wid = tid >> 6, lane = tid & 63;
  const int l16 = lane & 15, lg = lane >> 4;
  int bx = blockIdx.x, by = blockIdx.y;
  {  // XCD bijective remap; nwg = 8*393 = 3144 (%8 == 0)
    int gx = gridDim.x, nwg = gx * gridDim.y;
    int flat = by * gx + bx;
    int nf = (flat & 7) * (nwg >> 3) + (flat >> 3);
    bx = nf % gx; by = nf / gx;
  }
  const long m0 = (long)bx * 256, n0 = (long)by * 128;
  const int NT = K / 32;  // 32 (even)
  const int wm = wid >> 1, wn = wid & 1;

  const int brow = tid >> 2, bcp = tid & 3;
  const int bc = bcp ^ ((brow >> 1) & 3);
  int browg = (int)n0 + brow;
  if (browg > N - 1) browg = N - 1;
  const float* bsrc = Bt + (long)browg * K + bc * 8;

  fl4 bgE0, bgE1, bgO0, bgO1;
#define BLOADE(t)                                                               \
  {                                                                             \
    const float* p_ = bsrc + (t) * 32;                                          \
    asm volatile("global_load_dwordx4 %0, %1, off" : "=v"(bgE0) : "v"(p_));     \
    asm volatile("global_load_dwordx4 %0, %1, off" : "=v"(bgE1) : "v"(p_ + 4)); \
  }
#define BLOADO(t)                                                               \
  {                                                                             \
    const float* p_ = bsrc + (t) * 32;                                          \
    asm volatile("global_load_dwordx4 %0, %1, off" : "=v"(bgO0) : "v"(p_));     \
    asm volatile("global_load_dwordx4 %0, %1, off" : "=v"(bgO1) : "v"(p_ + 4)); \
  }
#define BWRITEE(b)                                                              \
  {                                                                             \
    bf16x8 o_;                                                                  \
    _Pragma("unroll")                                                           \
    for (int u_ = 0; u_ < 4; u_++) {                                            \
      o_[u_] = f2bf(bgE0[u_]);                                                  \
      o_[4 + u_] = f2bf(bgE1[u_]);                                              \
    }                                                                           \
    *(bf16x8*)(lds[b] + 256 * 32 + tid * 8) = o_;                               \
  }
#define BWRITEO(b)                                                              \
  {                                                                             \
    bf16x8 o_;                                                                  \
    _Pragma("unroll")                                                           \
    for (int u_ = 0; u_ < 4; u_++) {                                            \
      o_[u_] = f2bf(bgO0[u_]);                                                  \
      o_[4 + u_] = f2bf(bgO1[u_]);                                              \
    }                                                                           \
    *(bf16x8*)(lds[b] + 256 * 32 + tid * 8) = o_;                               \
  }
#define SA2(t, b)                                                               \
  {                                                                             \
    _Pragma("unroll")                                                           \
    for (int i_ = 0; i_ < 2; i_++) {                                            \
      int ca_ = i_ * 512 + tid;                                                 \
      int row_ = ca_ >> 2, cp_ = ca_ & 3, c_ = cp_ ^ ((row_ >> 1) & 3);         \
      gload_lds16(A + (m0 + row_) * (long)K + (t) * 32 + c_ * 8,                \
                  lds[b] + (i_ * 512 + wid * 64) * 8);                          \
    }                                                                           \
  }
#define COMPUTE(b)                                                              \
  {                                                                             \
    const short* As = lds[b];                                                   \
    const short* Bs = lds[b] + 256 * 32;                                        \
    bf16x8 bfr[4];                                                              \
    _Pragma("unroll")                                                           \
    for (int n = 0; n < 4; n++) {                                               \
      int row = wn * 64 + n * 16 + l16;                                         \
      bfr[n] = *(const bf16x8*)((const char*)Bs + row * 64 +                    \
                                ((lg ^ ((row >> 1) & 3)) * 16));                \
    }                                                                           \
    __builtin_amdgcn_s_setprio(1);                                              \
    _Pragma("unroll")                                                           \
    for (int m = 0; m < 4; m++) {                                               \
      int row = wm * 64 + m * 16 + l16;                                         \
      bf16x8 af = *(const bf16x8*)((const char*)As + row * 64 +                 \
                                   ((lg ^ ((row >> 1) & 3)) * 16));             \
      _Pragma("unroll")                                                         \
      for (int n = 0; n < 4; n++)                                               \
        acc[m][n] = __builtin_amdgcn_mfma_f32_16x16x32_bf16(af, bfr[n],         \
                                                            acc[m][n], 0, 0, 0);\
    }                                                                           \
    __builtin_amdgcn_s_setprio(0);                                              \
  }
#define TAILSYNC(s)                                                             \
  {                                                                             \
    if ((s) + 3 < NT) {                                                         \
      asm volatile("s_waitcnt vmcnt(4)" ::: "memory");                          \
    } else if ((s) + 2 < NT) {                                                  \
      asm volatile("s_waitcnt vmcnt(2)" ::: "memory");                          \
    } else if ((s) + 1 < NT) {                                                  \
      asm volatile("s_waitcnt vmcnt(0)" ::: "memory");                          \
    }                                                                           \
    if ((s) + 1 < NT) {                                                         \
      asm volatile("s_waitcnt lgkmcnt(0)" ::: "memory");                        \
      __builtin_amdgcn_s_barrier();                                             \
      __builtin_amdgcn_sched_barrier(0);                                        \
    }                                                                           \
  }

  f32x4 acc[4][4] = {};
  BLOADE(0);
  asm volatile("s_waitcnt vmcnt(0)" ::: "memory");
  __builtin_amdgcn_sched_barrier(0);
  BWRITEE(0);
  BLOADO(1);
  SA2(0, 0);
  SA2(1, 1);
  if (2 < NT) BLOADE(2);
  asm volatile("s_waitcnt vmcnt(4)" ::: "memory");
  asm volatile("s_waitcnt lgkmcnt(0)" ::: "memory");
  __builtin_amdgcn_s_barrier();
  __builtin_amdgcn_sched_barrier(0);

  for (int t = 0; t < NT; t += 2) {
    {  // even step s = t
      if (t + 1 < NT) BWRITEO((t + 1) % 3);
      if (t + 3 < NT) BLOADO(t + 3);
      if (t + 2 < NT) SA2(t + 2, (t + 2) % 3);
      COMPUTE(t % 3);
      TAILSYNC(t);
    }
    if (t + 1 < NT) {  // odd step s = t+1
      if (t + 2 < NT) BWRITEE((t + 2) % 3);
      if (t + 4 < NT) BLOADE(t + 4);
      if (t + 3 < NT) SA2(t + 3, (t + 3) % 3);
      COMPUTE((t + 1) % 3);
      TAILSYNC(t + 1);
    }
  }
#undef TAILSYNC
#undef COMPUTE
#undef SA2
#undef BWRITEO
#undef BWRITEE
#undef BLOADO
#undef BLOADE

  const int lr4 = lg * 4;
#pragma unroll
  for (int m = 0; m < 4; m++)
#pragma unroll
    for (int n = 0; n < 4; n++)
#pragma unroll
      for (int r = 0; r < 4; r++) {
        long row = m0 + wm * 64 + m * 16 + lr4 + r;
        long col = n0 + wn * 64 + n * 16 + l16;
        if (col < N) C[row * (long)N + col] = acc[m][n][r];
      }
}

// ---------------- MFMA flash attention, KVBLK=128, dbuf staging + setprio ----------------
__global__ __launch_bounds__(256) void attn_mfma(const short* __restrict__ qkv,
                                                 const short* __restrict__ vtg,
                                                 short* __restrict__ Oa) {
  int hh = blockIdx.x, qb = blockIdx.y;
  int q0 = qb * 64;
  int tid = threadIdx.x, wv = tid >> 6, lane = tid & 63;
  int l16 = lane & 15, lg = lane >> 4;
  int hcol = hh * 64;
  __shared__ short Ks[2][KVB * 64];
  __shared__ short Vt[2][64 * KVB];
  __shared__ short Pl[4][16 * KVB];

  bf16x8 qf[2];
  {
    const short* qrow = qkv + (long)(q0 + wv * 16 + l16) * QKVD + hcol;
#pragma unroll
    for (int dc = 0; dc < 2; dc++) {
      bf16x8 t = *(const bf16x8*)(qrow + dc * 32 + lg * 8);
#pragma unroll
      for (int j = 0; j < 8; j++) t[j] = f2bf(bf2f(t[j]) * 0.125f);
      qf[dc] = t;
    }
  }
  f32x4 of[4] = {};
  float mrun[4], lrun[4];
#pragma unroll
  for (int r = 0; r < 4; r++) { mrun[r] = -3e38f; lrun[r] = 0.f; }

#define STAGEKV(kt_, b_)                                                        \
  {                                                                             \
    int k0_ = (kt_) * KVB;                                                      \
    _Pragma("unroll")                                                           \
    for (int i = 0; i < 4; i++) {                                               \
      int ca = i * 256 + tid;                                                   \
      int row = ca >> 3, cp = ca & 7, c = cp ^ (row & 7);                       \
      gload_lds16(qkv + (long)(k0_ + row) * QKVD + DIM + hcol + c * 8,          \
                  (short*)Ks[b_] + (i * 256 + wv * 64) * 8);                    \
    }                                                                           \
    _Pragma("unroll")                                                           \
    for (int i = 0; i < 4; i++) {                                               \
      int ca = i * 256 + tid;                                                   \
      int row = ca >> 4, cp = ca & 15, c = cp ^ (row & 7);                      \
      gload_lds16(vtg + (long)(hcol + row) * SEQ + k0_ + c * 8,                 \
                  (short*)Vt[b_] + (i * 256 + wv * 64) * 8);                    \
    }                                                                           \
  }

  int nt = qb / 2 + 1;
  STAGEKV(0, 0);
  asm volatile("s_waitcnt vmcnt(0)" ::: "memory");
  __builtin_amdgcn_s_barrier();

  for (int kt = 0; kt < nt; kt++) {
    const int cur = kt & 1;
    if (kt + 1 < nt) STAGEKV(kt + 1, cur ^ 1);
    int k0 = kt * KVB;

    f32x4 sacc[8] = {};
    __builtin_amdgcn_s_setprio(1);
#pragma unroll
    for (int kc = 0; kc < 8; kc++) {
      int row = kc * 16 + l16;
#pragma unroll
      for (int dc = 0; dc < 2; dc++) {
        bf16x8 kf = *(const bf16x8*)((const char*)Ks[cur] + row * 128 + (((dc * 4 + lg) ^ (row & 7)) * 16));
        sacc[kc] = __builtin_amdgcn_mfma_f32_16x16x32_bf16(qf[dc], kf, sacc[kc], 0, 0, 0);
      }
    }
    __builtin_amdgcn_s_setprio(0);

    float sv[8][4], pf[8][4];
#pragma unroll
    for (int kc = 0; kc < 8; kc++)
#pragma unroll
      for (int r = 0; r < 4; r++) sv[kc][r] = sacc[kc][r];
    if (kt == nt - 1) {
#pragma unroll
      for (int kc = 0; kc < 8; kc++)
#pragma unroll
        for (int r = 0; r < 4; r++) {
          int kg = k0 + kc * 16 + l16;
          int rg = q0 + wv * 16 + lg * 4 + r;
          if (kg > rg) sv[kc][r] = -3e38f;
        }
    }
    float corr[4];
#pragma unroll
    for (int r = 0; r < 4; r++) {
      float m01 = fmaxf(sv[0][r], sv[1][r]), m23 = fmaxf(sv[2][r], sv[3][r]);
      float m45 = fmaxf(sv[4][r], sv[5][r]), m67 = fmaxf(sv[6][r], sv[7][r]);
      float mt = fmaxf(fmaxf(m01, m23), fmaxf(m45, m67));
#pragma unroll
      for (int o = 8; o >= 1; o >>= 1) mt = fmaxf(mt, __shfl_xor(mt, o));
      float mn = fmaxf(mrun[r], mt);
      corr[r] = __expf(mrun[r] - mn);
      mrun[r] = mn;
      float ps = 0.f;
#pragma unroll
      for (int kc = 0; kc < 8; kc++) {
        float p = __expf(sv[kc][r] - mn);
        pf[kc][r] = p;
        ps += p;
      }
#pragma unroll
      for (int o = 8; o >= 1; o >>= 1) ps += __shfl_xor(ps, o);
      lrun[r] = lrun[r] * corr[r] + ps;
    }
#pragma unroll
    for (int c = 0; c < 4; c++)
#pragma unroll
      for (int r = 0; r < 4; r++) of[c][r] *= corr[r];
#pragma unroll
    for (int kc = 0; kc < 8; kc++)
#pragma unroll
      for (int r = 0; r < 4; r++) {
        int row = lg * 4 + r, col = kc * 16 + l16;
        int chunk = col >> 3;
        *(short*)((char*)Pl[wv] + row * 256 + ((chunk ^ (row & 7)) * 16) + (col & 7) * 2) = f2bf(pf[kc][r]);
      }
    bf16x8 pfr[4];
#pragma unroll
    for (int kc2 = 0; kc2 < 4; kc2++) {
      int cl = kc2 * 4 + lg;
      pfr[kc2] = *(const bf16x8*)((const char*)Pl[wv] + l16 * 256 + ((cl ^ (l16 & 7)) * 16));
    }
    __builtin_amdgcn_s_setprio(1);
#pragma unroll
    for (int c = 0; c < 4; c++)
#pragma unroll
      for (int kc2 = 0; kc2 < 4; kc2++) {
        int vrow = c * 16 + l16;
        int cl = kc2 * 4 + lg;
        bf16x8 vf = *(const bf16x8*)((const char*)Vt[cur] + vrow * 256 + ((cl ^ (vrow & 7)) * 16));
        of[c] = __builtin_amdgcn_mfma_f32_16x16x32_bf16(pfr[kc2], vf, of[c], 0, 0, 0);
      }
    __builtin_amdgcn_s_setprio(0);
    if (kt + 1 < nt) {
      asm volatile("s_waitcnt vmcnt(0)" ::: "memory");
      __builtin_amdgcn_s_barrier();
      __builtin_amdgcn_sched_barrier(0);
    }
  }
#undef STAGEKV
#pragma unroll
  for (int c = 0; c < 4; c++)
#pragma unroll
    for (int r = 0; r < 4; r++) {
      int rowg = q0 + wv * 16 + lg * 4 + r;
      int colg = hcol + c * 16 + l16;
      Oa[(long)rowg * DIM + colg] = f2bf(of[c][r] / lrun[r]);
    }
}

// ---------------- orchestration ----------------
extern "C" void kernel_launch(void* const* d_in, const int* in_sizes, int n_in,
                              void* d_out, int out_size, void* d_ws, size_t ws_size,
                              hipStream_t stream) {
  const int* ids = (const int*)d_in[0];
  const float* tok = (const float*)d_in[1];
  const float* pos = (const float*)d_in[2];
  const float* Wq = (const float*)d_in[3];
  const float* bq = (const float*)d_in[4];
  const float* Wk = (const float*)d_in[5];
  const float* bk = (const float*)d_in[6];
  const float* Wv = (const float*)d_in[7];
  const float* bv = (const float*)d_in[8];
  const float* Wo = (const float*)d_in[9];
  const float* bo = (const float*)d_in[10];
  const float* W1 = (const float*)d_in[11];
  const float* b1 = (const float*)d_in[12];
  const float* W2 = (const float*)d_in[13];
  const float* b2 = (const float*)d_in[14];
  const float* ln1w = (const float*)d_in[15];
  const float* ln1b = (const float*)d_in[16];
  const float* ln2w = (const float*)d_in[17];
  const float* ln2b = (const float*)d_in[18];
  const float* lnfw = (const float*)d_in[19];
  const float* lnfb = (const float*)d_in[20];
  const float* lmh = (const float*)d_in[21];
  float* out = (float*)d_out;

  char* wsb = (char*)d_ws;
  float* h = (float*)wsb;                           // 8 MB fp32 residual
  short* x = (short*)(wsb + 8388608);               // 4 MB bf16 LN out
  char* big = wsb + 8388608 + 4194304;
  short* qkv  = (short*)big;                        // 12 MB   [S][3072]
  short* a    = (short*)(big + 12582912);           // 4 MB    [S][1024]
  short* vt   = (short*)(big + 16777216);           // 4 MB    [1024][S]
  short* fbuf = (short*)(big + 20971520);           // 16 MB   [S][4096]
  float* pproj = (float*)fbuf;                      // proj partials: 2x8MB (fbuf free then)
  char* wdyn = big + 37748736;
  short* wqkvT = (short*)wdyn;                      // 6 MB  [3072][1024]
  short* woT   = (short*)(wdyn + 6291456);          // 2 MB  [1024][1024]
  short* w1T   = (short*)(wdyn + 8388608);          // 8 MB  [4096][1024]
  short* w2T   = (short*)(wdyn + 16777216);         // 8 MB  [1024][4096]
  float* bias3 = (float*)(wdyn + 25165824);         // 12 KB
  float* pffn2 = (float*)(wsb + 79691776);          // 2x8MB at 76MB (ends 92MB)

  embed_kernel<<<(SEQ * DIM + 255) / 256, 256, 0, stream>>>(ids, tok, pos, h);
  ln_kernel<<<SEQ, 256, 0, stream>>>(h, ln1w, ln1b, x);  // layer 0 ln1

  dim3 gQKV(SEQ / 64, QKVD / 128);                  // 32 x 24 = 768
  dim3 gPROJ(SEQ / 64, DIM / 128, 2);               // 32 x 8 x 2 = 512
  dim3 gFFN1(SEQ / 128, FFN / 128);                 // 16 x 32 = 512
  dim3 gFFN2(SEQ / 64, DIM / 128, 2);               // 32 x 8 x 2 = 512 (NT=16)
  dim3 gV(SEQ / 256, (VOCAB + 127) / 128);          // 8 x 393 = 3144 (%8==0)

  for (int l = 0; l < NLAYER; l++) {
    Prep p;
    p.wq = Wq + (long)l * DIM * DIM; p.wk = Wk + (long)l * DIM * DIM;
    p.wv = Wv + (long)l * DIM * DIM; p.wo = Wo + (long)l * DIM * DIM;
    p.w1 = W1 + (long)l * DIM * FFN; p.w2 = W2 + (long)l * FFN * DIM;
    p.bq = bq + (long)l * DIM; p.bk = bk + (long)l * DIM; p.bv = bv + (long)l * DIM;
    p.qkvT = wqkvT; p.woT = woT; p.w1T = w1T; p.w2T = w2T; p.bias3 = bias3;
    prep_kernel<<<3073, 256, 0, stream>>>(p);

    gemm_small<false, true, true, 1, true><<<gQKV, 256, 0, stream>>>(x, wqkvT, bias3, qkv, QKVD, DIM);
    transpose_v<<<dim3(SEQ / 64, DIM / 64), 256, 0, stream>>>(qkv, vt);
    attn_mfma<<<dim3(NHEAD, SEQ / 64), 256, 0, stream>>>(qkv, vt, a);
    gemm_small<false, false, false, 2, true><<<gPROJ, 256, 0, stream>>>(a, woT, nullptr, pproj, DIM, DIM);
    reduce_ln<2><<<SEQ, 256, 0, stream>>>(pproj, bo + (long)l * DIM,
                                          ln2w + (long)l * DIM, ln2b + (long)l * DIM, h, x);
    gemm4<true, true, true, true><<<gFFN1, 256, 0, stream>>>(x, w1T, b1 + (long)l * FFN, fbuf, FFN, DIM);
    gemm_small<false, false, false, 2, true><<<gFFN2, 256, 0, stream>>>(fbuf, w2T, nullptr, pffn2, DIM, FFN);
    const float* nw = (l < NLAYER - 1) ? ln1w + (long)(l + 1) * DIM : lnfw;
    const float* nb = (l < NLAYER - 1) ? ln1b + (long)(l + 1) * DIM : lnfb;
    reduce_ln<2><<<SEQ, 256, 0, stream>>>(pffn2, b2 + (long)l * DIM, nw, nb, h, x);
  }

  gemm256b<<<gV, 512, 0, stream>>>(x, lmh, out, VOCAB, DIM);
}